// Round 1
// baseline (419.412 us; speedup 1.0000x reference)
//
#include <hip/hip_runtime.h>

#define USER_NUM 1000000
#define EMBED_DIM 64
#define BATCH 16384

// One 16-lane group per batch row. Each lane loads a float4 of each V row
// (16 lanes x 16B = 256B = full 64-dim fp32 row, perfectly coalesced).
// Reduce the partial dot across the 16-lane segment with shfl_xor.
__global__ __launch_bounds__(256) void fm_score_kernel(
    const int*   __restrict__ input,  // (BATCH, 2) int32
    const float* __restrict__ W,      // (1.5M, 1)
    const float* __restrict__ b,      // (1,)
    const float* __restrict__ V,      // (1.5M, 64)
    float*       __restrict__ out)    // (BATCH,)
{
    const int tid     = blockIdx.x * blockDim.x + threadIdx.x;
    const int row     = tid >> 4;          // 16 lanes per row
    const int sublane = tid & 15;
    if (row >= BATCH) return;

    const int uid = input[2 * row + 0];
    const int iid = input[2 * row + 1] + USER_NUM;

    const float4* vu = (const float4*)(V + (size_t)uid * EMBED_DIM) + sublane;
    const float4* vi = (const float4*)(V + (size_t)iid * EMBED_DIM) + sublane;

    float4 a = *vu;
    float4 c = *vi;
    float p = a.x * c.x + a.y * c.y + a.z * c.z + a.w * c.w;

    // reduce over the 16-lane segment
    p += __shfl_xor(p, 8, 16);
    p += __shfl_xor(p, 4, 16);
    p += __shfl_xor(p, 2, 16);
    p += __shfl_xor(p, 1, 16);

    if (sublane == 0) {
        out[row] = p + W[uid] + W[iid] + b[0];
    }
}

extern "C" void kernel_launch(void* const* d_in, const int* in_sizes, int n_in,
                              void* d_out, int out_size, void* d_ws, size_t ws_size,
                              hipStream_t stream) {
    const int*   input = (const int*)  d_in[0];
    const float* W     = (const float*)d_in[1];
    const float* b     = (const float*)d_in[2];
    const float* V     = (const float*)d_in[3];
    float*       out   = (float*)d_out;

    const int threads = 256;
    const int rows_per_block = threads / 16;           // 16
    const int grid = (BATCH + rows_per_block - 1) / rows_per_block;  // 1024

    fm_score_kernel<<<grid, threads, 0, stream>>>(input, W, b, V, out);
}

// Round 2
// 419.037 us; speedup vs baseline: 1.0009x; 1.0009x over previous
//
#include <hip/hip_runtime.h>

#define USER_NUM 1000000
#define EMBED_DIM 64
#define BATCH 16384

// One 16-lane group per batch row. Each lane loads a float4 of each V row
// (16 lanes x 16B = 256B = full 64-dim fp32 row, perfectly coalesced).
// Reduce the partial dot across the 16-lane segment with shfl_xor.
//
// grid*rows_per_block == BATCH exactly -> no bounds check.
// W/b gathers issued BEFORE the shuffle reduction so their HBM latency
// overlaps the cross-lane reduce (they're broadcast within the group).
__global__ __launch_bounds__(256) void fm_score_kernel(
    const int*   __restrict__ input,  // (BATCH, 2) int32
    const float* __restrict__ W,      // (1.5M, 1)
    const float* __restrict__ b,      // (1,)
    const float* __restrict__ V,      // (1.5M, 64)
    float*       __restrict__ out)    // (BATCH,)
{
    const int tid     = blockIdx.x * blockDim.x + threadIdx.x;
    const int row     = tid >> 4;          // 16 lanes per row
    const int sublane = tid & 15;

    const int2 idx = ((const int2*)input)[row];   // 8B broadcast load per group
    const int uid = idx.x;
    const int iid = idx.y + USER_NUM;

    const float4* vu = (const float4*)(V + (size_t)uid * EMBED_DIM) + sublane;
    const float4* vi = (const float4*)(V + (size_t)iid * EMBED_DIM) + sublane;

    float4 a = *vu;
    float4 c = *vi;

    // issue scalar gathers early; results needed only after the reduction
    const float wu = W[uid];
    const float wi = W[iid];
    const float bb = b[0];

    float p = a.x * c.x + a.y * c.y + a.z * c.z + a.w * c.w;

    // reduce over the 16-lane segment
    p += __shfl_xor(p, 8, 16);
    p += __shfl_xor(p, 4, 16);
    p += __shfl_xor(p, 2, 16);
    p += __shfl_xor(p, 1, 16);

    if (sublane == 0) {
        out[row] = p + wu + wi + bb;
    }
}

extern "C" void kernel_launch(void* const* d_in, const int* in_sizes, int n_in,
                              void* d_out, int out_size, void* d_ws, size_t ws_size,
                              hipStream_t stream) {
    const int*   input = (const int*)  d_in[0];
    const float* W     = (const float*)d_in[1];
    const float* b     = (const float*)d_in[2];
    const float* V     = (const float*)d_in[3];
    float*       out   = (float*)d_out;

    const int threads = 256;
    const int rows_per_block = threads / 16;                          // 16
    const int grid = (BATCH + rows_per_block - 1) / rows_per_block;   // 1024, exact

    fm_score_kernel<<<grid, threads, 0, stream>>>(input, W, b, V, out);
}